// Round 2
// baseline (778.531 us; speedup 1.0000x reference)
//
#include <hip/hip_runtime.h>
#include <hip/hip_cooperative_groups.h>
#include <stdint.h>

namespace cg = cooperative_groups;

typedef float f32x4 __attribute__((ext_vector_type(4)));
typedef int   i32x4 __attribute__((ext_vector_type(4)));
typedef int   i32x8 __attribute__((ext_vector_type(8)));

#define AS1 __attribute__((address_space(1)))
#define AS3 __attribute__((address_space(3)))

__device__ __forceinline__ void async_copy16(const void* g, void* l) {
    __builtin_amdgcn_global_load_lds((AS1 void*)(g), (AS3 void*)(l), 16, 0, 0);
}

// ---------------------------------------------------------------- fused prepass
// One cooperative kernel: zero amaxs -> grid.sync -> amax (4x-unrolled float4,
// wave+block reduce, 1 atomicMax/block) -> grid.sync -> quantize (4x-unrolled).
// grid = 1024 blocks (4/CU guaranteed by launch_bounds) so grid.sync is valid.
__device__ __forceinline__ unsigned pack_fp8x4(float4 v, float s) {
    float a = fminf(fmaxf(v.x * s, -448.0f), 448.0f);
    float b = fminf(fmaxf(v.y * s, -448.0f), 448.0f);
    float c = fminf(fmaxf(v.z * s, -448.0f), 448.0f);
    float d = fminf(fmaxf(v.w * s, -448.0f), 448.0f);
    int p = 0;
    p = __builtin_amdgcn_cvt_pk_fp8_f32(a, b, p, false);
    p = __builtin_amdgcn_cvt_pk_fp8_f32(c, d, p, true);
    return (unsigned)p;
}

__global__ __launch_bounds__(256, 4) void prep_kernel(
    const float4* __restrict__ inp, int n4i,
    const float4* __restrict__ wgt, int n4w,
    int nb_i, unsigned* __restrict__ amaxs,
    unsigned* __restrict__ qi, unsigned* __restrict__ qw)
{
    __shared__ float red[4];
    const int tid = threadIdx.x;
    const int bid = blockIdx.x;
    const bool isw = bid >= nb_i;
    const float4* x = isw ? wgt : inp;
    const int n4   = isw ? n4w : n4i;
    unsigned* q    = isw ? qw  : qi;
    const int lb   = isw ? bid - nb_i : bid;
    const int lnb  = isw ? (int)gridDim.x - nb_i : nb_i;

    cg::grid_group grid = cg::this_grid();

    // pass 0: zero the amax slots (workspace may be poisoned)
    if (bid == 0 && tid < 2) amaxs[tid] = 0u;
    grid.sync();

    // pass 1: amax
    const int idx = lb * 256 + tid;
    const int stride = lnb * 256;
    float m = 0.0f;
    int i = idx;
    for (; i + 3 * stride < n4; i += 4 * stride) {
        float4 v0 = x[i];
        float4 v1 = x[i + stride];
        float4 v2 = x[i + 2 * stride];
        float4 v3 = x[i + 3 * stride];
        float m0 = fmaxf(fmaxf(fabsf(v0.x), fabsf(v0.y)), fmaxf(fabsf(v0.z), fabsf(v0.w)));
        float m1 = fmaxf(fmaxf(fabsf(v1.x), fabsf(v1.y)), fmaxf(fabsf(v1.z), fabsf(v1.w)));
        float m2 = fmaxf(fmaxf(fabsf(v2.x), fabsf(v2.y)), fmaxf(fabsf(v2.z), fabsf(v2.w)));
        float m3 = fmaxf(fmaxf(fabsf(v3.x), fabsf(v3.y)), fmaxf(fabsf(v3.z), fabsf(v3.w)));
        m = fmaxf(m, fmaxf(fmaxf(m0, m1), fmaxf(m2, m3)));
    }
    for (; i < n4; i += stride) {
        float4 v = x[i];
        m = fmaxf(fmaxf(m, fmaxf(fabsf(v.x), fabsf(v.y))),
                  fmaxf(fabsf(v.z), fabsf(v.w)));
    }
#pragma unroll
    for (int off = 32; off > 0; off >>= 1)
        m = fmaxf(m, __shfl_down(m, off));
    if ((tid & 63) == 0) red[tid >> 6] = m;
    __syncthreads();
    if (tid == 0) {
        m = fmaxf(fmaxf(red[0], red[1]), fmaxf(red[2], red[3]));
        atomicMax(amaxs + (isw ? 1 : 0), __float_as_uint(m));
    }
    grid.sync();

    // pass 2: quantize (amax is device-visible after grid sync)
    const float amax = fmaxf(__uint_as_float(amaxs[isw ? 1 : 0]), 1e-12f);
    const float s = 448.0f / amax;
    i = idx;
    for (; i + 3 * stride < n4; i += 4 * stride) {
        float4 v0 = x[i];
        float4 v1 = x[i + stride];
        float4 v2 = x[i + 2 * stride];
        float4 v3 = x[i + 3 * stride];
        q[i]              = pack_fp8x4(v0, s);
        q[i + stride]     = pack_fp8x4(v1, s);
        q[i + 2 * stride] = pack_fp8x4(v2, s);
        q[i + 3 * stride] = pack_fp8x4(v3, s);
    }
    for (; i < n4; i += stride) q[i] = pack_fp8x4(x[i], s);
}

// ---------------------------------------------------------------- GEMM
// C[m,n] = sum_k A[m,k]*B[n,k]  (fp8 e4m3, K-major)  * scale + bias[n]
//
// 256x256 tile, 8 waves (2x4), per-wave C = 128x64 (8x4 16x16 frags).
// MFMA: mfma_scale_f32_16x16x128_f8f6f4 with e8m0 scales = 127 (x1.0).
// LDS: ring of 9 stage-steps x (A 8KB + B 8KB) = 144 KiB; step = 32 k-cols.
//   16B-unit placement swizzle (bank-conflict floor; counter-verified 0).
// Pipeline: per K-step {issue 4 stage-steps | phased ds_read + MFMA clusters,
//   NO intra-step barriers (staging is published only at boundaries) |
//   boundary s_waitcnt vmcnt(2) + s_barrier}. Reads/MFMA of desynced waves
//   overlap across the CU instead of lockstep-alternating.
#define RING 9
#define STEPB 8192

__global__ __launch_bounds__(512, 2) void gemm_fp8(
    const uint8_t* __restrict__ qA,
    const uint8_t* __restrict__ qB,
    const float*   __restrict__ bias,
    const unsigned* __restrict__ amaxs,
    float* __restrict__ out,
    int M, int N, int K)
{
    __shared__ uint8_t lds[2 * RING * STEPB];   // 144 KiB

    const int tid  = threadIdx.x;
    const int lane = tid & 63;
    const int wave = tid >> 6;
    const int wm   = wave >> 2;        // 0..1  (row half)
    const int wn   = wave & 3;         // 0..3  (col quarter)

    // XCD-aware bijective swizzle (grid = 688 = 8*86)
    const int ntiles = N >> 8;                       // 43
    const int per    = (int)gridDim.x >> 3;          // 86
    const int swz    = ((int)blockIdx.x & 7) * per + ((int)blockIdx.x >> 3);
    const int mtile  = swz / ntiles;
    const int ntile  = swz - mtile * ntiles;

    const int li   = lane & 15;
    const int lj   = lane >> 4;        // k-block of this lane's MFMA operand
    const int jx16 = lj << 4;
    const int ai32 = li << 5;

    uint8_t* ldsA = lds;
    uint8_t* ldsB = lds + RING * STEPB;
    const int wl = wave << 10;         // wave-uniform LDS slice base

    const uint8_t* gApan = qA + (size_t)(mtile << 8) * K;
    const uint8_t* gBpan = qB + (size_t)(ntile << 8) * K;

    // stage source pre-swizzle: thread tid loads the chunk (r,h) whose
    // swizzled unit index equals tid:  2r+h = tid ^ (u&3)
    int off[4];
#pragma unroll
    for (int g = 0; g < 4; ++g) {
        int x = tid ^ g;
        off[g] = (x >> 1) * K + (x & 1) * 16;
    }

#define STAGE(u_, su_, g_) do {                                              \
        async_copy16(gApan + (off[(g_)] + ((u_) << 5)),                      \
                     ldsA + ((su_) * STEPB + wl));                           \
        async_copy16(gBpan + (off[(g_)] + ((u_) << 5)),                      \
                     ldsB + ((su_) * STEPB + wl));                           \
    } while (0)

#define LDFRAG(dst_, base_, rowc_) do {                                      \
        int _o = (((rowc_) + ai32) ^ jx16);                                  \
        i32x4 _lo = *(const i32x4*)((base_) + _o);                           \
        i32x4 _hi = *(const i32x4*)((base_) + (_o ^ 16));                    \
        (dst_) = __builtin_shufflevector(_lo, _hi, 0, 1, 2, 3, 4, 5, 6, 7);  \
    } while (0)

#define MFMA(acc_, a_, b_)                                                   \
    (acc_) = __builtin_amdgcn_mfma_scale_f32_16x16x128_f8f6f4(               \
        (a_), (b_), (acc_), 0, 0, 0, 0x7F7F7F7F, 0, 0x7F7F7F7F)

    // prologue: stage steps 0..4 (slots 0..4); 0..3 needed for t=0
    STAGE(0, 0, 0); STAGE(1, 1, 1); STAGE(2, 2, 2); STAGE(3, 3, 3); STAGE(4, 4, 0);
    asm volatile("s_waitcnt vmcnt(2)" ::: "memory");
    __builtin_amdgcn_s_barrier();
    asm volatile("" ::: "memory");

    f32x4 acc[8][4] = {};
    i32x8 afr[4], bfr[4];

    const int rAc = wm << 12;          // 32 * (wm*128)
    const int rBc = wn << 11;          // 32 * (wn*64)
    const int NSTEP = K >> 7;          // 32 MFMA K-steps
    const int NSU   = K >> 5;          // 128 stage-steps

    int s4 = 0;                        // (4t) % RING
#pragma unroll 1
    for (int t = 0; t < NSTEP; ++t) {
        int sl = s4 + lj; if (sl >= RING) sl -= RING;   // per-lane ring slot
        const uint8_t* rdA = ldsA + sl * STEPB;
        const uint8_t* rdB = ldsB + sl * STEPB;
        const int u0 = (t << 2) + 5;

        // issue all 4 next stage-steps up front (8 vmem ops in flight)
        { int su = s4 + 5; if (su >= RING) su -= RING; if (u0     < NSU) STAGE(u0,     su, 1); }
        { int su = s4 + 6; if (su >= RING) su -= RING; if (u0 + 1 < NSU) STAGE(u0 + 1, su, 2); }
        { int su = s4 + 7; if (su >= RING) su -= RING; if (u0 + 2 < NSU) STAGE(u0 + 2, su, 3); }
        { int su = s4 + 8; if (su >= RING) su -= RING; if (u0 + 3 < NSU) STAGE(u0 + 3, su, 0); }

        // ---- phased reads + MFMA clusters, no barriers inside the step
        LDFRAG(afr[0], rdA, rAc + 0 * 512);
        LDFRAG(afr[1], rdA, rAc + 1 * 512);
        LDFRAG(afr[2], rdA, rAc + 2 * 512);
        LDFRAG(afr[3], rdA, rAc + 3 * 512);
        LDFRAG(bfr[0], rdB, rBc + 0 * 512);
        LDFRAG(bfr[1], rdB, rBc + 1 * 512);
        __builtin_amdgcn_s_setprio(1);
#pragma unroll
        for (int fi = 0; fi < 4; ++fi) {
            MFMA(acc[fi][0], afr[fi], bfr[0]);
            MFMA(acc[fi][1], afr[fi], bfr[1]);
        }
        __builtin_amdgcn_s_setprio(0);

        LDFRAG(bfr[2], rdB, rBc + 2 * 512);
        LDFRAG(bfr[3], rdB, rBc + 3 * 512);
        __builtin_amdgcn_s_setprio(1);
#pragma unroll
        for (int fi = 0; fi < 4; ++fi) {
            MFMA(acc[fi][2], afr[fi], bfr[2]);
            MFMA(acc[fi][3], afr[fi], bfr[3]);
        }
        __builtin_amdgcn_s_setprio(0);

        LDFRAG(afr[0], rdA, rAc + 2048 + 0 * 512);
        LDFRAG(afr[1], rdA, rAc + 2048 + 1 * 512);
        LDFRAG(afr[2], rdA, rAc + 2048 + 2 * 512);
        LDFRAG(afr[3], rdA, rAc + 2048 + 3 * 512);
        __builtin_amdgcn_s_setprio(1);
#pragma unroll
        for (int fi = 0; fi < 4; ++fi) {
            MFMA(acc[4 + fi][2], afr[fi], bfr[2]);
            MFMA(acc[4 + fi][3], afr[fi], bfr[3]);
        }
#pragma unroll
        for (int fi = 0; fi < 4; ++fi) {
            MFMA(acc[4 + fi][0], afr[fi], bfr[0]);
            MFMA(acc[4 + fi][1], afr[fi], bfr[1]);
        }
        __builtin_amdgcn_s_setprio(0);

        // ---- step boundary: counted drain (never 0 mid-loop), publish
        if (t == NSTEP - 2)      asm volatile("s_waitcnt vmcnt(0)" ::: "memory");
        else if (t <  NSTEP - 2) asm volatile("s_waitcnt vmcnt(2)" ::: "memory");
        __builtin_amdgcn_s_barrier();
        asm volatile("" ::: "memory");

        s4 += 4; if (s4 >= RING) s4 -= RING;
    }

    // --- epilogue
    const float amax_a = fmaxf(__uint_as_float(amaxs[0]), 1e-12f);
    const float amax_w = fmaxf(__uint_as_float(amaxs[1]), 1e-12f);
    const float scale = (amax_a * amax_w) * (1.0f / (448.0f * 448.0f));

    const int row0 = (mtile << 8) + (wm << 7) + (lj << 2);
    const int col0 = (ntile << 8) + (wn << 6) + li;
#pragma unroll
    for (int fj = 0; fj < 4; ++fj) {
        const int col = col0 + fj * 16;
        const float bv = bias[col];
#pragma unroll
        for (int fi = 0; fi < 8; ++fi) {
            const int row = row0 + fi * 16;
#pragma unroll
            for (int r = 0; r < 4; ++r)
                out[(size_t)(row + r) * N + col] = acc[fi][fj][r] * scale + bv;
        }
    }
#undef STAGE
#undef LDFRAG
#undef MFMA
}

// ---------------------------------------------------------------- launch
extern "C" void kernel_launch(void* const* d_in, const int* in_sizes, int n_in,
                              void* d_out, int out_size, void* d_ws, size_t ws_size,
                              hipStream_t stream) {
    const float* inp  = (const float*)d_in[0];
    const float* wgt  = (const float*)d_in[1];
    const float* bias = (const float*)d_in[2];
    float* out = (float*)d_out;

    const int N = in_sizes[2];              // 11008
    const int K = in_sizes[1] / N;          // 4096
    const int M = in_sizes[0] / K;          // 4096

    unsigned* amaxs = (unsigned*)d_ws;
    uint8_t* qin = (uint8_t*)d_ws + 256;
    uint8_t* qw  = qin + (size_t)M * K;

    int n4i = M * K / 4;
    int n4w = N * K / 4;
    int nb_i = 256;                          // of 1024 coop blocks (4/CU)

    const float4* inp4 = (const float4*)inp;
    const float4* wgt4 = (const float4*)wgt;
    unsigned* qi_p = (unsigned*)qin;
    unsigned* qw_p = (unsigned*)qw;
    void* args[] = { (void*)&inp4, (void*)&n4i, (void*)&wgt4, (void*)&n4w,
                     (void*)&nb_i, (void*)&amaxs, (void*)&qi_p, (void*)&qw_p };
    hipLaunchCooperativeKernel((const void*)prep_kernel, dim3(1024), dim3(256),
                               args, 0, stream);

    dim3 grid((M >> 8) * (N >> 8));          // 16 * 43 = 688 (mult of 8)
    gemm_fp8<<<grid, 512, 0, stream>>>(qin, qw, bias, amaxs, out, M, N, K);
}